// Round 10
// baseline (142.259 us; speedup 1.0000x reference)
//
#include <hip/hip_runtime.h>
#include <stdint.h>

#define DEVINL __device__ __forceinline__

typedef float f32x4 __attribute__((ext_vector_type(4)));
typedef float f32x2 __attribute__((ext_vector_type(2)));
typedef short s16x8 __attribute__((ext_vector_type(8)));
typedef short s16x4 __attribute__((ext_vector_type(4)));
typedef unsigned int u32x4 __attribute__((ext_vector_type(4)));

constexpr int Bb = 4, Hh = 16, Ss = 2048, Dd = 64;
constexpr float SCALE = 0.088388347648318447f;                     // 1/sqrt(128)
constexpr float QSC = 0.088388347648318447f * 1.4426950408889634f; // scale * log2(e)

DEVINL short f2bf(float x) {
  union { float f; unsigned u; } c; c.f = x;
  unsigned r = (c.u + 0x7fffu + ((c.u >> 16) & 1u)) >> 16;  // RNE
  return (short)r;
}

DEVINL unsigned pkbf(float a, float b) {
  unsigned r;
  asm("v_cvt_pk_bf16_f32 %0, %1, %2" : "=v"(r) : "v"(a), "v"(b));
  return r;
}

DEVINL void gload_lds16(const short* g, short* l) {
  __builtin_amdgcn_global_load_lds(
      (const __attribute__((address_space(1))) void*)g,
      (__attribute__((address_space(3))) void*)l, 16, 0, 0);
}

// ---------------- mask -> bitmask prepass (R4-proven) ----------------
__global__ void mask_to_bits(const int* __restrict__ mask,
                             unsigned long long* __restrict__ bits, int n) {
  int gid = blockIdx.x * blockDim.x + threadIdx.x;
  int stride = gridDim.x * blockDim.x;
  for (int i = gid; i < n; i += stride) {
    unsigned long long bal = __ballot(mask[i] != 0);
    if ((i & 63) == 0) bits[i >> 6] = bal;
  }
}

// ---------------- K/V -> swizzled bf16 tile-image prepass (R4-proven) --------
// K tile (bh,t): short[4096]; (kv,d) at kv*64 + ((4*(d&15) + (d>>4)) ^ ((kv&7)<<3))
// V tile (bh,t): short[4096]; (d,kv) at d*64  + ((4*(kv&15) + (kv>>4)) ^ ((d&7)<<3))
__global__ void kvconv(const float* __restrict__ K, const float* __restrict__ V,
                       short* __restrict__ Kimg, short* __restrict__ Vimg) {
  const int x = blockIdx.x;
  const int sel = x & 1;
  const int t = (x >> 1) & 31;
  const int bh = x >> 6;
  const int tid = threadIdx.x;
  if (sel == 0) {
    const float* Kp = K + ((size_t)bh * Ss + t * 64) * Dd;
    short* img = Kimg + ((size_t)bh * 32 + t) * 4096;
#pragma unroll
    for (int it = 0; it < 4; ++it) {
      int idx = tid + it * 256;
      int kv = idx >> 4, c = idx & 15;
      const float* kr = Kp + (size_t)kv * Dd;
      s16x4 sv;
      sv[0] = f2bf(kr[c]);
      sv[1] = f2bf(kr[c + 16]);
      sv[2] = f2bf(kr[c + 32]);
      sv[3] = f2bf(kr[c + 48]);
      *(s16x4*)(img + kv * 64 + ((4 * c) ^ ((kv & 7) << 3))) = sv;
    }
  } else {
    const float* Vp = V + ((size_t)bh * Ss + t * 64) * Dd;
    short* img = Vimg + ((size_t)bh * 32 + t) * 4096;
    const int d = tid & 63, c4 = tid >> 6;
#pragma unroll
    for (int it = 0; it < 4; ++it) {
      int c = c4 * 4 + it;
      s16x4 sv;
      sv[0] = f2bf(Vp[(size_t)(c) * Dd + d]);
      sv[1] = f2bf(Vp[(size_t)(c + 16) * Dd + d]);
      sv[2] = f2bf(Vp[(size_t)(c + 32) * Dd + d]);
      sv[3] = f2bf(Vp[(size_t)(c + 48) * Dd + d]);
      *(s16x4*)(img + d * 64 + ((4 * c) ^ ((d & 7) << 3))) = sv;
    }
  }
}

// ---------------- main attention (R4 numerics, qs=4 amortized tile) ----------
// 4 waves x 64 q-rows (q-tile 256), grid 512, XCD-bijective swizzle (R6-proven
// decode). K/V fragments read from LDS ONCE per tile into registers and reused
// across all 4 q-subtiles -> LDS reads per score HALVED vs R4. Bias C-init
// (0 keep / -1e9 drop, log2 domain), exp2-only softmax, l via ones-row MFMA.
__launch_bounds__(256, 2)
__global__ void attn2(const float* __restrict__ Q,
                      const unsigned long long* __restrict__ mbits,
                      const short* __restrict__ Kimg,
                      const short* __restrict__ Vimg,
                      float* __restrict__ Out) {
  __shared__ short lds[16384];  // 2 bufs x (K 4096 | V 4096) shorts = 32 KB

  const int tid = threadIdx.x;
  const int lane = tid & 63;
  const int w = tid >> 6;
  const int l15 = lane & 15;
  const int lq = lane >> 4;

  // bijective XCD swizzle (R6-proven): 512 = 8 * 64
  const int nb = ((blockIdx.x & 7) << 6) | (blockIdx.x >> 3);
  const int qt = nb & 7;        // 8 q-tiles of 256
  const int bh = nb >> 3;       // 0..63
  const int b = bh >> 4;

  const float* Qp = Q + (size_t)bh * Ss * Dd;
  float* Op = Out + (size_t)bh * Ss * Dd;
  const short* Kt = Kimg + (size_t)bh * 32 * 4096;
  const short* Vt = Vimg + (size_t)bh * 32 * 4096;
  const int qbW = qt * 256 + w * 64;   // wave's first q row (64 rows/wave)

  // Q fragments (B-operand), scale*log2e folded in
  s16x8 qf[4][2];
#pragma unroll
  for (int qs = 0; qs < 4; ++qs) {
    const float* qrow = Qp + (size_t)(qbW + qs * 16 + l15) * Dd;
#pragma unroll
    for (int dh = 0; dh < 2; ++dh) {
      s16x8 f;
#pragma unroll
      for (int g = 0; g < 4; ++g) {
        f32x2 v = *(const f32x2*)(qrow + 16 * g + 4 * lq + 2 * dh);
        f[g] = f2bf(v[0] * QSC);
        f[g + 4] = f2bf(v[1] * QSC);
      }
      qf[qs][dh] = f;
    }
  }

  // constant ones A-fragment: row 0 = 1.0bf16, rows 1..15 = 0 (k-map agnostic)
  s16x8 onesA;
  {
    short o = (l15 == 0) ? (short)0x3F80 : (short)0;
#pragma unroll
    for (int j = 0; j < 8; ++j) onesA[j] = o;
  }

  f32x4 oacc[4][4];
  f32x4 lacc[4];
#pragma unroll
  for (int qs = 0; qs < 4; ++qs) {
    lacc[qs] = f32x4{0.f, 0.f, 0.f, 0.f};
#pragma unroll
    for (int ds = 0; ds < 4; ++ds) oacc[qs][ds] = f32x4{0.f, 0.f, 0.f, 0.f};
  }

  // loop-invariant fragment offsets (identical for K and V images)
  int off[4][2];
#pragma unroll
  for (int sub = 0; sub < 4; ++sub) {
    int row = sub * 16 + l15;
    int sw = (row & 7) << 3;
    off[sub][0] = row * 64 + ((16 * lq) ^ sw);
    off[sub][1] = row * 64 + ((16 * lq + 8) ^ sw);
  }

  // mask-bit row base: row q = qbW + qs*16 + l15 -> mbq + qs*512 + t (R6-proven)
  const unsigned long long* mbq = mbits + (size_t)(b * Ss + qbW + l15) * 32;

  auto stage = [&](int buf, int t) {
    short* Lb = lds + buf * 8192;
    const short* gk = Kt + t * 4096 + w * 512 + lane * 8;
    const short* gv = Vt + t * 4096 + w * 512 + lane * 8;
    gload_lds16(gk, Lb + w * 512);
    gload_lds16(gk + 2048, Lb + 2048 + w * 512);
    gload_lds16(gv, Lb + 4096 + w * 512);
    gload_lds16(gv + 2048, Lb + 6144 + w * 512);
  };

  stage(0, 0);

  for (int t = 0; t < 32; ++t) {
    const int cur = t & 1;
    // load mask words early (latency hidden under barrier + fragment loads)
    unsigned long long mw[4];
#pragma unroll
    for (int qs = 0; qs < 4; ++qs) mw[qs] = mbq[qs * 512 + t];

    __syncthreads();  // drains vmcnt -> buf[cur] ready; prev reads done
    if (t < 31) stage(cur ^ 1, t + 1);

    const short* kb = lds + cur * 8192;
    const short* vb = kb + 4096;

    // ---- K/V fragments: read ONCE per tile, reused across 4 q-subtiles
    s16x8 kf[4][2], vf[4][2];
#pragma unroll
    for (int sub = 0; sub < 4; ++sub) {
      kf[sub][0] = *(const s16x8*)(kb + off[sub][0]);
      kf[sub][1] = *(const s16x8*)(kb + off[sub][1]);
      vf[sub][0] = *(const s16x8*)(vb + off[sub][0]);
      vf[sub][1] = *(const s16x8*)(vb + off[sub][1]);
    }

#pragma unroll
    for (int qs = 0; qs < 4; ++qs) {
      // ---- mask bias (R4-proven): keep-bit=1 -> 0, bit=0 -> -1e9
      f32x4 sc[4];
      {
        const unsigned mlo = ~(unsigned)(mw[qs] >> (4 * lq));
        const unsigned mhi = ~(unsigned)(mw[qs] >> (32 + 4 * lq));
#pragma unroll
        for (int sub = 0; sub < 4; ++sub) {
          const unsigned wsrc = (sub < 2) ? mlo : mhi;
          const int base = 16 * (sub & 1);
#pragma unroll
          for (int r = 0; r < 4; ++r) {
            int sb = ((int)(wsrc << (31 - (base + r)))) >> 31;  // keep->0, drop->-1
            sc[sub][r] = __uint_as_float((unsigned)sb & 0xCE6E6B28u);  // 0 or -1e9
          }
        }
      }
      // ---- QK^T (S^T = K*Q^T) with bias C-init
      __builtin_amdgcn_s_setprio(1);
#pragma unroll
      for (int sub = 0; sub < 4; ++sub) {
        sc[sub] = __builtin_amdgcn_mfma_f32_16x16x32_bf16(kf[sub][0], qf[qs][0], sc[sub], 0, 0, 0);
        sc[sub] = __builtin_amdgcn_mfma_f32_16x16x32_bf16(kf[sub][1], qf[qs][1], sc[sub], 0, 0, 0);
      }
      __builtin_amdgcn_s_setprio(0);
      // ---- exp2 + pack to bf16 P fragments
#pragma unroll
      for (int sub = 0; sub < 4; ++sub) {
        f32x4 s = sc[sub];
#pragma unroll
        for (int r = 0; r < 4; ++r) s[r] = __builtin_amdgcn_exp2f(s[r]);
        sc[sub] = s;
      }
      s16x8 pf[2];
#pragma unroll
      for (int kvh = 0; kvh < 2; ++kvh) {
        u32x4 wv;
        wv[0] = pkbf(sc[0][2 * kvh], sc[1][2 * kvh]);
        wv[1] = pkbf(sc[2][2 * kvh], sc[3][2 * kvh]);
        wv[2] = pkbf(sc[0][2 * kvh + 1], sc[1][2 * kvh + 1]);
        wv[3] = pkbf(sc[2][2 * kvh + 1], sc[3][2 * kvh + 1]);
        pf[kvh] = __builtin_bit_cast(s16x8, wv);
      }
      // ---- PV (O^T += V^T * P^T) + l via ones-row MFMA
      __builtin_amdgcn_s_setprio(1);
#pragma unroll
      for (int ds = 0; ds < 4; ++ds) {
        f32x4 a = oacc[qs][ds];
        a = __builtin_amdgcn_mfma_f32_16x16x32_bf16(vf[ds][0], pf[0], a, 0, 0, 0);
        oacc[qs][ds] = __builtin_amdgcn_mfma_f32_16x16x32_bf16(vf[ds][1], pf[1], a, 0, 0, 0);
      }
      lacc[qs] = __builtin_amdgcn_mfma_f32_16x16x32_bf16(onesA, pf[0], lacc[qs], 0, 0, 0);
      lacc[qs] = __builtin_amdgcn_mfma_f32_16x16x32_bf16(onesA, pf[1], lacc[qs], 0, 0, 0);
      __builtin_amdgcn_s_setprio(0);
    }
  }

  // epilogue: l lives in row 0 (lanes lq==0, reg 0); broadcast, divide, store
#pragma unroll
  for (int qs = 0; qs < 4; ++qs) {
    float l = __shfl(lacc[qs][0], l15);  // lane l15 holds l for q-col l15
    float inv = 1.f / l;
    float* orow = Op + (size_t)(qbW + qs * 16 + l15) * Dd;
#pragma unroll
    for (int ds = 0; ds < 4; ++ds) {
      f32x4 v = oacc[qs][ds];
      v *= inv;
      *(f32x4*)(orow + ds * 16 + 4 * lq) = v;
    }
  }
}

// ---------------- fallback (round-1 kernel, proven) ----------------
template<bool USEBITS>
__launch_bounds__(256, 2)
__global__ void attn_fwd(const float* __restrict__ Q, const float* __restrict__ K,
                         const float* __restrict__ V, const int* __restrict__ mask,
                         const unsigned long long* __restrict__ mbits,
                         float* __restrict__ Out) {
  __shared__ short Ks[64 * 64];
  __shared__ short Vs[64 * 64];

  const int tid = threadIdx.x;
  const int lane = tid & 63;
  const int w = tid >> 6;
  const int l15 = lane & 15;
  const int lq = lane >> 4;

  const int bid = blockIdx.x;
  const int h = bid & 15;
  const int qt = (bid >> 4) & 7;
  const int b = bid >> 7;

  const int bh = b * Hh + h;
  const float* Qp = Q + (size_t)bh * Ss * Dd;
  const float* Kp = K + (size_t)bh * Ss * Dd;
  const float* Vp = V + (size_t)bh * Ss * Dd;
  float* Op = Out + (size_t)bh * Ss * Dd;

  const int qbW = qt * 256 + w * 64;

  s16x8 qf[4][2];
#pragma unroll
  for (int qs = 0; qs < 4; ++qs) {
    const float* qrow = Qp + (size_t)(qbW + qs * 16 + l15) * Dd;
#pragma unroll
    for (int dh = 0; dh < 2; ++dh) {
      s16x8 f;
#pragma unroll
      for (int g = 0; g < 4; ++g) {
        f32x2 v = *(const f32x2*)(qrow + 16 * g + 4 * lq + 2 * dh);
        f[g] = f2bf(v[0]);
        f[g + 4] = f2bf(v[1]);
      }
      qf[qs][dh] = f;
    }
  }

  f32x4 oacc[4][4];
  float mrun[4], lrun[4];
#pragma unroll
  for (int qs = 0; qs < 4; ++qs) {
    mrun[qs] = -1e30f;
    lrun[qs] = 0.f;
#pragma unroll
    for (int ds = 0; ds < 4; ++ds) oacc[qs][ds] = f32x4{0.f, 0.f, 0.f, 0.f};
  }

  for (int kv0 = 0; kv0 < Ss; kv0 += 64) {
    __syncthreads();
#pragma unroll
    for (int p = 0; p < 4; ++p) {
      int f = tid + p * 256;
      int kv = f >> 4;
      int c = f & 15;
      const float* krow = Kp + (size_t)(kv0 + kv) * Dd;
      s16x4 sv;
      sv[0] = f2bf(krow[c]);
      sv[1] = f2bf(krow[c + 16]);
      sv[2] = f2bf(krow[c + 32]);
      sv[3] = f2bf(krow[c + 48]);
      *(s16x4*)(Ks + kv * 64 + ((4 * c) ^ ((kv & 7) << 3))) = sv;
    }
#pragma unroll
    for (int p = 0; p < 4; ++p) {
      int f = tid + p * 256;
      int kv = f >> 4;
      int c = f & 15;
      f32x4 v = *(const f32x4*)(Vp + (size_t)(kv0 + kv) * Dd + 4 * c);
      int pv = (kv & 15) * 4 + (kv >> 4);
#pragma unroll
      for (int i = 0; i < 4; ++i) {
        int d = 4 * c + i;
        Vs[d * 64 + (pv ^ ((d & 7) << 3))] = f2bf(v[i]);
      }
    }
    __syncthreads();

    s16x8 kf[4][2];
#pragma unroll
    for (int sub = 0; sub < 4; ++sub) {
      int row = sub * 16 + l15;
      const short* base = Ks + row * 64;
      int sw = (row & 7) << 3;
      kf[sub][0] = *(const s16x8*)(base + ((16 * lq + 0) ^ sw));
      kf[sub][1] = *(const s16x8*)(base + ((16 * lq + 8) ^ sw));
    }
    s16x8 vf[4][2];
#pragma unroll
    for (int ds = 0; ds < 4; ++ds) {
      int row = ds * 16 + l15;
      const short* base = Vs + row * 64;
      int sw = (row & 7) << 3;
      vf[ds][0] = *(const s16x8*)(base + ((16 * lq + 0) ^ sw));
      vf[ds][1] = *(const s16x8*)(base + ((16 * lq + 8) ^ sw));
    }

    const int kvw = kv0 >> 6;
#pragma unroll
    for (int qs = 0; qs < 4; ++qs) {
      f32x4 sc[4];
#pragma unroll
      for (int sub = 0; sub < 4; ++sub) {
        f32x4 a = f32x4{0.f, 0.f, 0.f, 0.f};
        a = __builtin_amdgcn_mfma_f32_16x16x32_bf16(kf[sub][0], qf[qs][0], a, 0, 0, 0);
        a = __builtin_amdgcn_mfma_f32_16x16x32_bf16(kf[sub][1], qf[qs][1], a, 0, 0, 0);
        sc[sub] = a;
      }

      const int q = qbW + qs * 16 + l15;
      unsigned long long mw = 0;
      if constexpr (USEBITS) mw = mbits[(size_t)(b * Ss + q) * 32 + kvw];

      float tm = -3e38f;
#pragma unroll
      for (int sub = 0; sub < 4; ++sub) {
        f32x4 s = sc[sub];
        if constexpr (USEBITS) {
          unsigned nib = (unsigned)((mw >> (16 * sub + 4 * lq)) & 0xFULL);
#pragma unroll
          for (int r = 0; r < 4; ++r) {
            float sv = s[r] * SCALE;
            sv = ((nib >> r) & 1u) ? sv : -1e9f;
            s[r] = sv;
            tm = fmaxf(tm, sv);
          }
        } else {
          const int* mrow = mask + ((size_t)b * Ss + q) * Ss + kv0 + 16 * sub + 4 * lq;
          int4 mi = *(const int4*)mrow;
          int mv[4] = {mi.x, mi.y, mi.z, mi.w};
#pragma unroll
          for (int r = 0; r < 4; ++r) {
            float sv = s[r] * SCALE;
            sv = mv[r] ? sv : -1e9f;
            s[r] = sv;
            tm = fmaxf(tm, sv);
          }
        }
        sc[sub] = s;
      }
      tm = fmaxf(tm, __shfl_xor(tm, 16));
      tm = fmaxf(tm, __shfl_xor(tm, 32));
      float mnew = fmaxf(mrun[qs], tm);
      float corr = __expf(mrun[qs] - mnew);
      mrun[qs] = mnew;

      float ps = 0.f;
#pragma unroll
      for (int sub = 0; sub < 4; ++sub) {
        f32x4 s = sc[sub];
#pragma unroll
        for (int r = 0; r < 4; ++r) {
          float p = __expf(s[r] - mnew);
          s[r] = p;
          ps += p;
        }
        sc[sub] = s;
      }
      ps += __shfl_xor(ps, 16);
      ps += __shfl_xor(ps, 32);
      lrun[qs] = lrun[qs] * corr + ps;
#pragma unroll
      for (int ds = 0; ds < 4; ++ds) oacc[qs][ds] *= corr;

      s16x8 pf[2];
#pragma unroll
      for (int kvh = 0; kvh < 2; ++kvh) {
        s16x8 f;
#pragma unroll
        for (int j = 0; j < 8; ++j) f[j] = f2bf(sc[j & 3][2 * kvh + (j >> 2)]);
        pf[kvh] = f;
      }
#pragma unroll
      for (int ds = 0; ds < 4; ++ds) {
        f32x4 a = oacc[qs][ds];
        a = __builtin_amdgcn_mfma_f32_16x16x32_bf16(vf[ds][0], pf[0], a, 0, 0, 0);
        a = __builtin_amdgcn_mfma_f32_16x16x32_bf16(vf[ds][1], pf[1], a, 0, 0, 0);
        oacc[qs][ds] = a;
      }
    }
  }

#pragma unroll
  for (int qs = 0; qs < 4; ++qs) {
    float inv = 1.f / lrun[qs];
    float* orow = Op + (size_t)(qbW + qs * 16 + l15) * Dd;
#pragma unroll
    for (int ds = 0; ds < 4; ++ds) {
      f32x4 v = oacc[qs][ds];
      v *= inv;
      *(f32x4*)(orow + ds * 16 + 4 * lq) = v;
    }
  }
}

extern "C" void kernel_launch(void* const* d_in, const int* in_sizes, int n_in,
                              void* d_out, int out_size, void* d_ws, size_t ws_size,
                              hipStream_t stream) {
  const float* Q = (const float*)d_in[0];
  const float* K = (const float*)d_in[1];
  const float* V = (const float*)d_in[2];
  const int* mask = (const int*)d_in[5];
  float* out = (float*)d_out;

  const int nmask = Bb * Ss * Ss;
  const size_t bitsB = (size_t)(nmask / 64) * 8;          // 2 MiB
  const size_t imgB = (size_t)Bb * Hh * 32 * 4096 * 2;    // 16 MiB each
  const size_t need = bitsB + 2 * imgB;                   // 34 MiB

  if (d_ws && ws_size >= need) {
    unsigned long long* bits = (unsigned long long*)d_ws;
    short* Kimg = (short*)((char*)d_ws + bitsB);
    short* Vimg = (short*)((char*)d_ws + bitsB + imgB);
    mask_to_bits<<<2048, 256, 0, stream>>>(mask, bits, nmask);
    kvconv<<<Bb * Hh * 32 * 2, 256, 0, stream>>>(K, V, Kimg, Vimg);
    attn2<<<512, 256, 0, stream>>>(Q, bits, Kimg, Vimg, out);
  } else if (d_ws && ws_size >= bitsB) {
    unsigned long long* bits = (unsigned long long*)d_ws;
    mask_to_bits<<<2048, 256, 0, stream>>>(mask, bits, nmask);
    attn_fwd<true><<<Bb * Hh * (Ss / 256), 256, 0, stream>>>(Q, K, V, mask, bits, out);
  } else {
    attn_fwd<false><<<Bb * Hh * (Ss / 256), 256, 0, stream>>>(Q, K, V, mask, nullptr, out);
  }
}

// Round 11
// 134.410 us; speedup vs baseline: 1.0584x; 1.0584x over previous
//
#include <hip/hip_runtime.h>
#include <stdint.h>

#define DEVINL __device__ __forceinline__

typedef float f32x4 __attribute__((ext_vector_type(4)));
typedef float f32x2 __attribute__((ext_vector_type(2)));
typedef short s16x8 __attribute__((ext_vector_type(8)));
typedef short s16x4 __attribute__((ext_vector_type(4)));
typedef unsigned int u32x4 __attribute__((ext_vector_type(4)));

constexpr int Bb = 4, Hh = 16, Ss = 2048, Dd = 64;
constexpr float SCALE = 0.088388347648318447f;                     // 1/sqrt(128)
constexpr float QSC = 0.088388347648318447f * 1.4426950408889634f; // scale * log2(e)

DEVINL short f2bf(float x) {
  union { float f; unsigned u; } c; c.f = x;
  unsigned r = (c.u + 0x7fffu + ((c.u >> 16) & 1u)) >> 16;  // RNE
  return (short)r;
}

DEVINL unsigned pkbf(float a, float b) {
  unsigned r;
  asm("v_cvt_pk_bf16_f32 %0, %1, %2" : "=v"(r) : "v"(a), "v"(b));
  return r;
}

DEVINL void gload_lds16(const short* g, short* l) {
  __builtin_amdgcn_global_load_lds(
      (const __attribute__((address_space(1))) void*)g,
      (__attribute__((address_space(3))) void*)l, 16, 0, 0);
}

// ---------------- mask -> bitmask prepass ----------------
__global__ void mask_to_bits(const int* __restrict__ mask,
                             unsigned long long* __restrict__ bits, int n) {
  int gid = blockIdx.x * blockDim.x + threadIdx.x;
  int stride = gridDim.x * blockDim.x;
  for (int i = gid; i < n; i += stride) {
    unsigned long long bal = __ballot(mask[i] != 0);
    if ((i & 63) == 0) bits[i >> 6] = bal;
  }
}

// ---------------- K/V -> swizzled bf16 tile-image prepass ----------------
// K image tile (bh,t): short[4096]; element (kv,d) at kv*64 + ((4*(d&15) + (d>>4)) ^ ((kv&7)<<3))
// V image tile (bh,t): short[4096]; element (d,kv) at d*64  + ((4*(kv&15) + (kv>>4)) ^ ((d&7)<<3))
__global__ void kvconv(const float* __restrict__ K, const float* __restrict__ V,
                       short* __restrict__ Kimg, short* __restrict__ Vimg) {
  const int x = blockIdx.x;
  const int sel = x & 1;
  const int t = (x >> 1) & 31;
  const int bh = x >> 6;
  const int tid = threadIdx.x;
  if (sel == 0) {
    const float* Kp = K + ((size_t)bh * Ss + t * 64) * Dd;
    short* img = Kimg + ((size_t)bh * 32 + t) * 4096;
#pragma unroll
    for (int it = 0; it < 4; ++it) {
      int idx = tid + it * 256;
      int kv = idx >> 4, c = idx & 15;
      const float* kr = Kp + (size_t)kv * Dd;
      s16x4 sv;
      sv[0] = f2bf(kr[c]);
      sv[1] = f2bf(kr[c + 16]);
      sv[2] = f2bf(kr[c + 32]);
      sv[3] = f2bf(kr[c + 48]);
      *(s16x4*)(img + kv * 64 + ((4 * c) ^ ((kv & 7) << 3))) = sv;
    }
  } else {
    const float* Vp = V + ((size_t)bh * Ss + t * 64) * Dd;
    short* img = Vimg + ((size_t)bh * 32 + t) * 4096;
    const int d = tid & 63, c4 = tid >> 6;
#pragma unroll
    for (int it = 0; it < 4; ++it) {
      int c = c4 * 4 + it;
      s16x4 sv;
      sv[0] = f2bf(Vp[(size_t)(c) * Dd + d]);
      sv[1] = f2bf(Vp[(size_t)(c + 16) * Dd + d]);
      sv[2] = f2bf(Vp[(size_t)(c + 32) * Dd + d]);
      sv[3] = f2bf(Vp[(size_t)(c + 48) * Dd + d]);
      *(s16x4*)(img + d * 64 + ((4 * c) ^ ((d & 7) << 3))) = sv;
    }
  }
}

// ---------------- main attention kernel (prepassed images) ----------------
// 4 waves x 32 q-rows (q-tile 128), grid = 1024 -> 4 blocks/CU.
// Mask folded into QK^T accumulator init (bias 0 for keep / -1e9 for drop,
// log2 domain) -> softmax body is exp2-only; row-sum l via ones-row MFMA.
// [R4 champion: attn2 107.9us, total 134.3us; 81% combined VALU+MFMA issue]
__launch_bounds__(256, 4)
__global__ void attn2(const float* __restrict__ Q,
                      const unsigned long long* __restrict__ mbits,
                      const short* __restrict__ Kimg,
                      const short* __restrict__ Vimg,
                      float* __restrict__ Out) {
  __shared__ short lds[16384];  // 2 bufs x (K 4096 | V 4096) shorts = 32 KB

  const int tid = threadIdx.x;
  const int lane = tid & 63;
  const int w = tid >> 6;
  const int l15 = lane & 15;
  const int lq = lane >> 4;

  const int bid = blockIdx.x;
  const int h = bid & 15;
  const int qt = (bid >> 4) & 15;
  const int b = bid >> 8;
  const int bh = b * Hh + h;

  const float* Qp = Q + (size_t)bh * Ss * Dd;
  float* Op = Out + (size_t)bh * Ss * Dd;
  const short* Kt = Kimg + (size_t)bh * 32 * 4096;
  const short* Vt = Vimg + (size_t)bh * 32 * 4096;
  const int qbW = qt * 128 + w * 32;

  // Q fragments (B-operand), scale*log2e folded in
  s16x8 qf[2][2];
#pragma unroll
  for (int qs = 0; qs < 2; ++qs) {
    const float* qrow = Qp + (size_t)(qbW + qs * 16 + l15) * Dd;
#pragma unroll
    for (int dh = 0; dh < 2; ++dh) {
      s16x8 f;
#pragma unroll
      for (int g = 0; g < 4; ++g) {
        f32x2 v = *(const f32x2*)(qrow + 16 * g + 4 * lq + 2 * dh);
        f[g] = f2bf(v[0] * QSC);
        f[g + 4] = f2bf(v[1] * QSC);
      }
      qf[qs][dh] = f;
    }
  }

  // constant ones A-fragment: row 0 = 1.0bf16, rows 1..15 = 0 (k-map agnostic)
  s16x8 onesA;
  {
    short o = (l15 == 0) ? (short)0x3F80 : (short)0;
#pragma unroll
    for (int j = 0; j < 8; ++j) onesA[j] = o;
  }

  f32x4 oacc[2][4];
  f32x4 lacc[2];
#pragma unroll
  for (int qs = 0; qs < 2; ++qs) {
    lacc[qs] = f32x4{0.f, 0.f, 0.f, 0.f};
#pragma unroll
    for (int ds = 0; ds < 4; ++ds) oacc[qs][ds] = f32x4{0.f, 0.f, 0.f, 0.f};
  }

  // loop-invariant fragment offsets (identical for K and V images)
  int off[4][2];
#pragma unroll
  for (int sub = 0; sub < 4; ++sub) {
    int row = sub * 16 + l15;
    int sw = (row & 7) << 3;
    off[sub][0] = row * 64 + ((16 * lq) ^ sw);
    off[sub][1] = row * 64 + ((16 * lq + 8) ^ sw);
  }

  // per-qs mask-bit row pointers
  const unsigned long long* mbq[2];
#pragma unroll
  for (int qs = 0; qs < 2; ++qs)
    mbq[qs] = mbits + (size_t)(b * Ss + qbW + qs * 16 + l15) * 32;

  auto stage = [&](int buf, int t) {
    short* Lb = lds + buf * 8192;
    const short* gk = Kt + t * 4096 + w * 512 + lane * 8;
    const short* gv = Vt + t * 4096 + w * 512 + lane * 8;
    gload_lds16(gk, Lb + w * 512);
    gload_lds16(gk + 2048, Lb + 2048 + w * 512);
    gload_lds16(gv, Lb + 4096 + w * 512);
    gload_lds16(gv + 2048, Lb + 6144 + w * 512);
  };

  stage(0, 0);

  for (int t = 0; t < 32; ++t) {
    const int cur = t & 1;
    // load mask words early (latency hidden under barrier + QK^T)
    unsigned long long mw0 = mbq[0][t];
    unsigned long long mw1 = mbq[1][t];
    __syncthreads();  // drains vmcnt -> buf[cur] ready; prev reads done
    if (t < 31) stage(cur ^ 1, t + 1);

    const short* kb = lds + cur * 8192;
    const short* vb = kb + 4096;

    // ---- mask bias: keep-bit=1 -> 0, bit=0 -> -1e9 (invert, sext, and)
    f32x4 bias[2][4];
#pragma unroll
    for (int qs = 0; qs < 2; ++qs) {
      const unsigned long long mw = qs ? mw1 : mw0;
      const unsigned mlo = ~(unsigned)(mw >> (4 * lq));
      const unsigned mhi = ~(unsigned)(mw >> (32 + 4 * lq));
#pragma unroll
      for (int sub = 0; sub < 4; ++sub) {
        const unsigned wsrc = (sub < 2) ? mlo : mhi;
        const int base = 16 * (sub & 1);
#pragma unroll
        for (int r = 0; r < 4; ++r) {
          int sb = ((int)(wsrc << (31 - (base + r)))) >> 31;  // keep -> 0, drop -> -1
          bias[qs][sub][r] = __uint_as_float((unsigned)sb & 0xCE6E6B28u);  // 0 or -1e9
        }
      }
    }

    // ---- QK^T (S^T = K*Q^T) with bias as C-init, streamed K fragments
    f32x4 sc[2][4];
    __builtin_amdgcn_s_setprio(1);
#pragma unroll
    for (int sub = 0; sub < 4; ++sub) {
      s16x8 k0 = *(const s16x8*)(kb + off[sub][0]);
      s16x8 k1 = *(const s16x8*)(kb + off[sub][1]);
#pragma unroll
      for (int qs = 0; qs < 2; ++qs) {
        f32x4 a = bias[qs][sub];
        a = __builtin_amdgcn_mfma_f32_16x16x32_bf16(k0, qf[qs][0], a, 0, 0, 0);
        a = __builtin_amdgcn_mfma_f32_16x16x32_bf16(k1, qf[qs][1], a, 0, 0, 0);
        sc[qs][sub] = a;
      }
    }
    __builtin_amdgcn_s_setprio(0);

    // ---- softmax numerator: exp2 only (mask already in scores) + P->bf16
    s16x8 pf[2][2];
#pragma unroll
    for (int qs = 0; qs < 2; ++qs) {
#pragma unroll
      for (int sub = 0; sub < 4; ++sub) {
        f32x4 s = sc[qs][sub];
#pragma unroll
        for (int r = 0; r < 4; ++r) s[r] = __builtin_amdgcn_exp2f(s[r]);
        sc[qs][sub] = s;
      }
#pragma unroll
      for (int kvh = 0; kvh < 2; ++kvh) {
        u32x4 wv;
        wv[0] = pkbf(sc[qs][0][2 * kvh], sc[qs][1][2 * kvh]);
        wv[1] = pkbf(sc[qs][2][2 * kvh], sc[qs][3][2 * kvh]);
        wv[2] = pkbf(sc[qs][0][2 * kvh + 1], sc[qs][1][2 * kvh + 1]);
        wv[3] = pkbf(sc[qs][2][2 * kvh + 1], sc[qs][3][2 * kvh + 1]);
        pf[qs][kvh] = __builtin_bit_cast(s16x8, wv);
      }
    }

    // ---- PV (O^T += V^T * P^T) + l via ones-row MFMA
    __builtin_amdgcn_s_setprio(1);
#pragma unroll
    for (int ds = 0; ds < 4; ++ds) {
      s16x8 v0 = *(const s16x8*)(vb + off[ds][0]);
      s16x8 v1 = *(const s16x8*)(vb + off[ds][1]);
#pragma unroll
      for (int qs = 0; qs < 2; ++qs) {
        f32x4 a = oacc[qs][ds];
        a = __builtin_amdgcn_mfma_f32_16x16x32_bf16(v0, pf[qs][0], a, 0, 0, 0);
        a = __builtin_amdgcn_mfma_f32_16x16x32_bf16(v1, pf[qs][1], a, 0, 0, 0);
        oacc[qs][ds] = a;
      }
    }
#pragma unroll
    for (int qs = 0; qs < 2; ++qs) {
      lacc[qs] = __builtin_amdgcn_mfma_f32_16x16x32_bf16(onesA, pf[qs][0], lacc[qs], 0, 0, 0);
      lacc[qs] = __builtin_amdgcn_mfma_f32_16x16x32_bf16(onesA, pf[qs][1], lacc[qs], 0, 0, 0);
    }
    __builtin_amdgcn_s_setprio(0);
  }

  // epilogue: l lives in row 0 (lanes lq==0, reg 0); broadcast, divide, store
#pragma unroll
  for (int qs = 0; qs < 2; ++qs) {
    float l = __shfl(lacc[qs][0], l15);  // lane l15 holds l for q-col l15
    float inv = 1.f / l;
    float* orow = Op + (size_t)(qbW + qs * 16 + l15) * Dd;
#pragma unroll
    for (int ds = 0; ds < 4; ++ds) {
      f32x4 v = oacc[qs][ds];
      v *= inv;
      *(f32x4*)(orow + ds * 16 + 4 * lq) = v;
    }
  }
}

// ---------------- fallback (round-1 kernel, proven) ----------------
template<bool USEBITS>
__launch_bounds__(256, 2)
__global__ void attn_fwd(const float* __restrict__ Q, const float* __restrict__ K,
                         const float* __restrict__ V, const int* __restrict__ mask,
                         const unsigned long long* __restrict__ mbits,
                         float* __restrict__ Out) {
  __shared__ short Ks[64 * 64];
  __shared__ short Vs[64 * 64];

  const int tid = threadIdx.x;
  const int lane = tid & 63;
  const int w = tid >> 6;
  const int l15 = lane & 15;
  const int lq = lane >> 4;

  const int bid = blockIdx.x;
  const int h = bid & 15;
  const int qt = (bid >> 4) & 7;
  const int b = bid >> 7;

  const int bh = b * Hh + h;
  const float* Qp = Q + (size_t)bh * Ss * Dd;
  const float* Kp = K + (size_t)bh * Ss * Dd;
  const float* Vp = V + (size_t)bh * Ss * Dd;
  float* Op = Out + (size_t)bh * Ss * Dd;

  const int qbW = qt * 256 + w * 64;

  s16x8 qf[4][2];
#pragma unroll
  for (int qs = 0; qs < 4; ++qs) {
    const float* qrow = Qp + (size_t)(qbW + qs * 16 + l15) * Dd;
#pragma unroll
    for (int dh = 0; dh < 2; ++dh) {
      s16x8 f;
#pragma unroll
      for (int g = 0; g < 4; ++g) {
        f32x2 v = *(const f32x2*)(qrow + 16 * g + 4 * lq + 2 * dh);
        f[g] = f2bf(v[0]);
        f[g + 4] = f2bf(v[1]);
      }
      qf[qs][dh] = f;
    }
  }

  f32x4 oacc[4][4];
  float mrun[4], lrun[4];
#pragma unroll
  for (int qs = 0; qs < 4; ++qs) {
    mrun[qs] = -1e30f;
    lrun[qs] = 0.f;
#pragma unroll
    for (int ds = 0; ds < 4; ++ds) oacc[qs][ds] = f32x4{0.f, 0.f, 0.f, 0.f};
  }

  for (int kv0 = 0; kv0 < Ss; kv0 += 64) {
    __syncthreads();
#pragma unroll
    for (int p = 0; p < 4; ++p) {
      int f = tid + p * 256;
      int kv = f >> 4;
      int c = f & 15;
      const float* krow = Kp + (size_t)(kv0 + kv) * Dd;
      s16x4 sv;
      sv[0] = f2bf(krow[c]);
      sv[1] = f2bf(krow[c + 16]);
      sv[2] = f2bf(krow[c + 32]);
      sv[3] = f2bf(krow[c + 48]);
      *(s16x4*)(Ks + kv * 64 + ((4 * c) ^ ((kv & 7) << 3))) = sv;
    }
#pragma unroll
    for (int p = 0; p < 4; ++p) {
      int f = tid + p * 256;
      int kv = f >> 4;
      int c = f & 15;
      f32x4 v = *(const f32x4*)(Vp + (size_t)(kv0 + kv) * Dd + 4 * c);
      int pv = (kv & 15) * 4 + (kv >> 4);
#pragma unroll
      for (int i = 0; i < 4; ++i) {
        int d = 4 * c + i;
        Vs[d * 64 + (pv ^ ((d & 7) << 3))] = f2bf(v[i]);
      }
    }
    __syncthreads();

    s16x8 kf[4][2];
#pragma unroll
    for (int sub = 0; sub < 4; ++sub) {
      int row = sub * 16 + l15;
      const short* base = Ks + row * 64;
      int sw = (row & 7) << 3;
      kf[sub][0] = *(const s16x8*)(base + ((16 * lq + 0) ^ sw));
      kf[sub][1] = *(const s16x8*)(base + ((16 * lq + 8) ^ sw));
    }
    s16x8 vf[4][2];
#pragma unroll
    for (int ds = 0; ds < 4; ++ds) {
      int row = ds * 16 + l15;
      const short* base = Vs + row * 64;
      int sw = (row & 7) << 3;
      vf[ds][0] = *(const s16x8*)(base + ((16 * lq + 0) ^ sw));
      vf[ds][1] = *(const s16x8*)(base + ((16 * lq + 8) ^ sw));
    }

    const int kvw = kv0 >> 6;
#pragma unroll
    for (int qs = 0; qs < 4; ++qs) {
      f32x4 sc[4];
#pragma unroll
      for (int sub = 0; sub < 4; ++sub) {
        f32x4 a = f32x4{0.f, 0.f, 0.f, 0.f};
        a = __builtin_amdgcn_mfma_f32_16x16x32_bf16(kf[sub][0], qf[qs][0], a, 0, 0, 0);
        a = __builtin_amdgcn_mfma_f32_16x16x32_bf16(kf[sub][1], qf[qs][1], a, 0, 0, 0);
        sc[sub] = a;
      }

      const int q = qbW + qs * 16 + l15;
      unsigned long long mw = 0;
      if constexpr (USEBITS) mw = mbits[(size_t)(b * Ss + q) * 32 + kvw];

      float tm = -3e38f;
#pragma unroll
      for (int sub = 0; sub < 4; ++sub) {
        f32x4 s = sc[sub];
        if constexpr (USEBITS) {
          unsigned nib = (unsigned)((mw >> (16 * sub + 4 * lq)) & 0xFULL);
#pragma unroll
          for (int r = 0; r < 4; ++r) {
            float sv = s[r] * SCALE;
            sv = ((nib >> r) & 1u) ? sv : -1e9f;
            s[r] = sv;
            tm = fmaxf(tm, sv);
          }
        } else {
          const int* mrow = mask + ((size_t)b * Ss + q) * Ss + kv0 + 16 * sub + 4 * lq;
          int4 mi = *(const int4*)mrow;
          int mv[4] = {mi.x, mi.y, mi.z, mi.w};
#pragma unroll
          for (int r = 0; r < 4; ++r) {
            float sv = s[r] * SCALE;
            sv = mv[r] ? sv : -1e9f;
            s[r] = sv;
            tm = fmaxf(tm, sv);
          }
        }
        sc[sub] = s;
      }
      tm = fmaxf(tm, __shfl_xor(tm, 16));
      tm = fmaxf(tm, __shfl_xor(tm, 32));
      float mnew = fmaxf(mrun[qs], tm);
      float corr = __expf(mrun[qs] - mnew);
      mrun[qs] = mnew;

      float ps = 0.f;
#pragma unroll
      for (int sub = 0; sub < 4; ++sub) {
        f32x4 s = sc[sub];
#pragma unroll
        for (int r = 0; r < 4; ++r) {
          float p = __expf(s[r] - mnew);
          s[r] = p;
          ps += p;
        }
        sc[sub] = s;
      }
      ps += __shfl_xor(ps, 16);
      ps += __shfl_xor(ps, 32);
      lrun[qs] = lrun[qs] * corr + ps;
#pragma unroll
      for (int ds = 0; ds < 4; ++ds) oacc[qs][ds] *= corr;

      s16x8 pf[2];
#pragma unroll
      for (int kvh = 0; kvh < 2; ++kvh) {
        s16x8 f;
#pragma unroll
        for (int j = 0; j < 8; ++j) f[j] = f2bf(sc[j & 3][2 * kvh + (j >> 2)]);
        pf[kvh] = f;
      }
#pragma unroll
      for (int ds = 0; ds < 4; ++ds) {
        f32x4 a = oacc[qs][ds];
        a = __builtin_amdgcn_mfma_f32_16x16x32_bf16(vf[ds][0], pf[0], a, 0, 0, 0);
        a = __builtin_amdgcn_mfma_f32_16x16x32_bf16(vf[ds][1], pf[1], a, 0, 0, 0);
        oacc[qs][ds] = a;
      }
    }
  }

#pragma unroll
  for (int qs = 0; qs < 4; ++qs) {
    float inv = 1.f / lrun[qs];
    float* orow = Op + (size_t)(qbW + qs * 16 + l15) * Dd;
#pragma unroll
    for (int ds = 0; ds < 4; ++ds) {
      f32x4 v = oacc[qs][ds];
      v *= inv;
      *(f32x4*)(orow + ds * 16 + 4 * lq) = v;
    }
  }
}

extern "C" void kernel_launch(void* const* d_in, const int* in_sizes, int n_in,
                              void* d_out, int out_size, void* d_ws, size_t ws_size,
                              hipStream_t stream) {
  const float* Q = (const float*)d_in[0];
  const float* K = (const float*)d_in[1];
  const float* V = (const float*)d_in[2];
  const int* mask = (const int*)d_in[5];
  float* out = (float*)d_out;

  const int nmask = Bb * Ss * Ss;
  const size_t bitsB = (size_t)(nmask / 64) * 8;          // 2 MiB
  const size_t imgB = (size_t)Bb * Hh * 32 * 4096 * 2;    // 16 MiB each
  const size_t need = bitsB + 2 * imgB;                   // 34 MiB

  if (d_ws && ws_size >= need) {
    unsigned long long* bits = (unsigned long long*)d_ws;
    short* Kimg = (short*)((char*)d_ws + bitsB);
    short* Vimg = (short*)((char*)d_ws + bitsB + imgB);
    mask_to_bits<<<2048, 256, 0, stream>>>(mask, bits, nmask);
    kvconv<<<Bb * Hh * 32 * 2, 256, 0, stream>>>(K, V, Kimg, Vimg);
    attn2<<<Bb * Hh * (Ss / 128), 256, 0, stream>>>(Q, bits, Kimg, Vimg, out);
  } else if (d_ws && ws_size >= bitsB) {
    unsigned long long* bits = (unsigned long long*)d_ws;
    mask_to_bits<<<2048, 256, 0, stream>>>(mask, bits, nmask);
    attn_fwd<true><<<Bb * Hh * (Ss / 256), 256, 0, stream>>>(Q, K, V, mask, bits, out);
  } else {
    attn_fwd<false><<<Bb * Hh * (Ss / 256), 256, 0, stream>>>(Q, K, V, mask, nullptr, out);
  }
}

// Round 12
// 132.629 us; speedup vs baseline: 1.0726x; 1.0134x over previous
//
#include <hip/hip_runtime.h>
#include <stdint.h>

#define DEVINL __device__ __forceinline__

typedef float f32x4 __attribute__((ext_vector_type(4)));
typedef float f32x2 __attribute__((ext_vector_type(2)));
typedef short s16x8 __attribute__((ext_vector_type(8)));
typedef short s16x4 __attribute__((ext_vector_type(4)));
typedef unsigned int u32x4 __attribute__((ext_vector_type(4)));

constexpr int Bb = 4, Hh = 16, Ss = 2048, Dd = 64;
constexpr float SCALE = 0.088388347648318447f;                     // 1/sqrt(128)
constexpr float QSC = 0.088388347648318447f * 1.4426950408889634f; // scale * log2(e)

DEVINL short f2bf(float x) {
  union { float f; unsigned u; } c; c.f = x;
  unsigned r = (c.u + 0x7fffu + ((c.u >> 16) & 1u)) >> 16;  // RNE
  return (short)r;
}

DEVINL unsigned pkbf(float a, float b) {
  unsigned r;
  asm("v_cvt_pk_bf16_f32 %0, %1, %2" : "=v"(r) : "v"(a), "v"(b));
  return r;
}

DEVINL void gload_lds16(const short* g, short* l) {
  __builtin_amdgcn_global_load_lds(
      (const __attribute__((address_space(1))) void*)g,
      (__attribute__((address_space(3))) void*)l, 16, 0, 0);
}

// ---------------- mask -> bitmask prepass ----------------
__global__ void mask_to_bits(const int* __restrict__ mask,
                             unsigned long long* __restrict__ bits, int n) {
  int gid = blockIdx.x * blockDim.x + threadIdx.x;
  int stride = gridDim.x * blockDim.x;
  for (int i = gid; i < n; i += stride) {
    unsigned long long bal = __ballot(mask[i] != 0);
    if ((i & 63) == 0) bits[i >> 6] = bal;
  }
}

// ---------------- K/V -> swizzled bf16 tile-image prepass ----------------
// K image tile (bh,t): short[4096]; element (kv,d) at kv*64 + ((4*(d&15) + (d>>4)) ^ ((kv&7)<<3))
// V image tile (bh,t): short[4096]; element (d,kv) at d*64  + ((4*(kv&15) + (kv>>4)) ^ ((d&7)<<3))
__global__ void kvconv(const float* __restrict__ K, const float* __restrict__ V,
                       short* __restrict__ Kimg, short* __restrict__ Vimg) {
  const int x = blockIdx.x;
  const int sel = x & 1;
  const int t = (x >> 1) & 31;
  const int bh = x >> 6;
  const int tid = threadIdx.x;
  if (sel == 0) {
    const float* Kp = K + ((size_t)bh * Ss + t * 64) * Dd;
    short* img = Kimg + ((size_t)bh * 32 + t) * 4096;
#pragma unroll
    for (int it = 0; it < 4; ++it) {
      int idx = tid + it * 256;
      int kv = idx >> 4, c = idx & 15;
      const float* kr = Kp + (size_t)kv * Dd;
      s16x4 sv;
      sv[0] = f2bf(kr[c]);
      sv[1] = f2bf(kr[c + 16]);
      sv[2] = f2bf(kr[c + 32]);
      sv[3] = f2bf(kr[c + 48]);
      *(s16x4*)(img + kv * 64 + ((4 * c) ^ ((kv & 7) << 3))) = sv;
    }
  } else {
    const float* Vp = V + ((size_t)bh * Ss + t * 64) * Dd;
    short* img = Vimg + ((size_t)bh * 32 + t) * 4096;
    const int d = tid & 63, c4 = tid >> 6;
#pragma unroll
    for (int it = 0; it < 4; ++it) {
      int c = c4 * 4 + it;
      s16x4 sv;
      sv[0] = f2bf(Vp[(size_t)(c) * Dd + d]);
      sv[1] = f2bf(Vp[(size_t)(c + 16) * Dd + d]);
      sv[2] = f2bf(Vp[(size_t)(c + 32) * Dd + d]);
      sv[3] = f2bf(Vp[(size_t)(c + 48) * Dd + d]);
      *(s16x4*)(img + d * 64 + ((4 * c) ^ ((d & 7) << 3))) = sv;
    }
  }
}

// ---------------- main attention kernel (prepassed images) ----------------
// 4 waves x 32 q-rows (q-tile 128), grid = 1024 -> 4 blocks/CU.
// Mask folded into QK^T accumulator init (bias 0 keep / -1e9 drop, log2
// domain) -> softmax body exp2-only; row-sum l via ones-row MFMA.
// R12 delta vs champion: mask words software-pipelined one tile ahead --
// loaded right AFTER the barrier (so the next barrier's vmcnt(0) drain finds
// them complete) instead of right before it (which exposed ~L2 latency per
// tile at every barrier drain).
__launch_bounds__(256, 4)
__global__ void attn2(const float* __restrict__ Q,
                      const unsigned long long* __restrict__ mbits,
                      const short* __restrict__ Kimg,
                      const short* __restrict__ Vimg,
                      float* __restrict__ Out) {
  __shared__ short lds[16384];  // 2 bufs x (K 4096 | V 4096) shorts = 32 KB

  const int tid = threadIdx.x;
  const int lane = tid & 63;
  const int w = tid >> 6;
  const int l15 = lane & 15;
  const int lq = lane >> 4;

  const int bid = blockIdx.x;
  const int h = bid & 15;
  const int qt = (bid >> 4) & 15;
  const int b = bid >> 8;
  const int bh = b * Hh + h;

  const float* Qp = Q + (size_t)bh * Ss * Dd;
  float* Op = Out + (size_t)bh * Ss * Dd;
  const short* Kt = Kimg + (size_t)bh * 32 * 4096;
  const short* Vt = Vimg + (size_t)bh * 32 * 4096;
  const int qbW = qt * 128 + w * 32;

  // Q fragments (B-operand), scale*log2e folded in
  s16x8 qf[2][2];
#pragma unroll
  for (int qs = 0; qs < 2; ++qs) {
    const float* qrow = Qp + (size_t)(qbW + qs * 16 + l15) * Dd;
#pragma unroll
    for (int dh = 0; dh < 2; ++dh) {
      s16x8 f;
#pragma unroll
      for (int g = 0; g < 4; ++g) {
        f32x2 v = *(const f32x2*)(qrow + 16 * g + 4 * lq + 2 * dh);
        f[g] = f2bf(v[0] * QSC);
        f[g + 4] = f2bf(v[1] * QSC);
      }
      qf[qs][dh] = f;
    }
  }

  // constant ones A-fragment: row 0 = 1.0bf16, rows 1..15 = 0 (k-map agnostic)
  s16x8 onesA;
  {
    short o = (l15 == 0) ? (short)0x3F80 : (short)0;
#pragma unroll
    for (int j = 0; j < 8; ++j) onesA[j] = o;
  }

  f32x4 oacc[2][4];
  f32x4 lacc[2];
#pragma unroll
  for (int qs = 0; qs < 2; ++qs) {
    lacc[qs] = f32x4{0.f, 0.f, 0.f, 0.f};
#pragma unroll
    for (int ds = 0; ds < 4; ++ds) oacc[qs][ds] = f32x4{0.f, 0.f, 0.f, 0.f};
  }

  // loop-invariant fragment offsets (identical for K and V images)
  int off[4][2];
#pragma unroll
  for (int sub = 0; sub < 4; ++sub) {
    int row = sub * 16 + l15;
    int sw = (row & 7) << 3;
    off[sub][0] = row * 64 + ((16 * lq) ^ sw);
    off[sub][1] = row * 64 + ((16 * lq + 8) ^ sw);
  }

  // per-qs mask-bit row pointers
  const unsigned long long* mbq[2];
#pragma unroll
  for (int qs = 0; qs < 2; ++qs)
    mbq[qs] = mbits + (size_t)(b * Ss + qbW + qs * 16 + l15) * 32;

  auto stage = [&](int buf, int t) {
    short* Lb = lds + buf * 8192;
    const short* gk = Kt + t * 4096 + w * 512 + lane * 8;
    const short* gv = Vt + t * 4096 + w * 512 + lane * 8;
    gload_lds16(gk, Lb + w * 512);
    gload_lds16(gk + 2048, Lb + 2048 + w * 512);
    gload_lds16(gv, Lb + 4096 + w * 512);
    gload_lds16(gv + 2048, Lb + 6144 + w * 512);
  };

  stage(0, 0);
  // prologue: tile-0 mask words (drained once by the first barrier)
  unsigned long long mw0 = mbq[0][0];
  unsigned long long mw1 = mbq[1][0];

  for (int t = 0; t < 32; ++t) {
    const int cur = t & 1;
    __syncthreads();  // drains vmcnt -> buf[cur] + mw(t) ready; prev reads done
    // issue next tile's staging AND mask loads now: both get the whole tile's
    // compute (~800cy) to land before the next barrier's vmcnt(0) drain.
    unsigned long long mwn0 = 0, mwn1 = 0;
    if (t < 31) {
      stage(cur ^ 1, t + 1);
      mwn0 = mbq[0][t + 1];
      mwn1 = mbq[1][t + 1];
    }

    const short* kb = lds + cur * 8192;
    const short* vb = kb + 4096;

    // ---- mask bias: keep-bit=1 -> 0, bit=0 -> -1e9 (invert, sext, and)
    f32x4 bias[2][4];
#pragma unroll
    for (int qs = 0; qs < 2; ++qs) {
      const unsigned long long mw = qs ? mw1 : mw0;
      const unsigned mlo = ~(unsigned)(mw >> (4 * lq));
      const unsigned mhi = ~(unsigned)(mw >> (32 + 4 * lq));
#pragma unroll
      for (int sub = 0; sub < 4; ++sub) {
        const unsigned wsrc = (sub < 2) ? mlo : mhi;
        const int base = 16 * (sub & 1);
#pragma unroll
        for (int r = 0; r < 4; ++r) {
          int sb = ((int)(wsrc << (31 - (base + r)))) >> 31;  // keep -> 0, drop -> -1
          bias[qs][sub][r] = __uint_as_float((unsigned)sb & 0xCE6E6B28u);  // 0 or -1e9
        }
      }
    }

    // ---- QK^T (S^T = K*Q^T) with bias as C-init, streamed K fragments
    f32x4 sc[2][4];
    __builtin_amdgcn_s_setprio(1);
#pragma unroll
    for (int sub = 0; sub < 4; ++sub) {
      s16x8 k0 = *(const s16x8*)(kb + off[sub][0]);
      s16x8 k1 = *(const s16x8*)(kb + off[sub][1]);
#pragma unroll
      for (int qs = 0; qs < 2; ++qs) {
        f32x4 a = bias[qs][sub];
        a = __builtin_amdgcn_mfma_f32_16x16x32_bf16(k0, qf[qs][0], a, 0, 0, 0);
        a = __builtin_amdgcn_mfma_f32_16x16x32_bf16(k1, qf[qs][1], a, 0, 0, 0);
        sc[qs][sub] = a;
      }
    }
    __builtin_amdgcn_s_setprio(0);

    // ---- softmax numerator: exp2 only (mask already in scores) + P->bf16
    s16x8 pf[2][2];
#pragma unroll
    for (int qs = 0; qs < 2; ++qs) {
#pragma unroll
      for (int sub = 0; sub < 4; ++sub) {
        f32x4 s = sc[qs][sub];
#pragma unroll
        for (int r = 0; r < 4; ++r) s[r] = __builtin_amdgcn_exp2f(s[r]);
        sc[qs][sub] = s;
      }
#pragma unroll
      for (int kvh = 0; kvh < 2; ++kvh) {
        u32x4 wv;
        wv[0] = pkbf(sc[qs][0][2 * kvh], sc[qs][1][2 * kvh]);
        wv[1] = pkbf(sc[qs][2][2 * kvh], sc[qs][3][2 * kvh]);
        wv[2] = pkbf(sc[qs][0][2 * kvh + 1], sc[qs][1][2 * kvh + 1]);
        wv[3] = pkbf(sc[qs][2][2 * kvh + 1], sc[qs][3][2 * kvh + 1]);
        pf[qs][kvh] = __builtin_bit_cast(s16x8, wv);
      }
    }

    // ---- PV (O^T += V^T * P^T) + l via ones-row MFMA
    __builtin_amdgcn_s_setprio(1);
#pragma unroll
    for (int ds = 0; ds < 4; ++ds) {
      s16x8 v0 = *(const s16x8*)(vb + off[ds][0]);
      s16x8 v1 = *(const s16x8*)(vb + off[ds][1]);
#pragma unroll
      for (int qs = 0; qs < 2; ++qs) {
        f32x4 a = oacc[qs][ds];
        a = __builtin_amdgcn_mfma_f32_16x16x32_bf16(v0, pf[qs][0], a, 0, 0, 0);
        a = __builtin_amdgcn_mfma_f32_16x16x32_bf16(v1, pf[qs][1], a, 0, 0, 0);
        oacc[qs][ds] = a;
      }
    }
#pragma unroll
    for (int qs = 0; qs < 2; ++qs) {
      lacc[qs] = __builtin_amdgcn_mfma_f32_16x16x32_bf16(onesA, pf[qs][0], lacc[qs], 0, 0, 0);
      lacc[qs] = __builtin_amdgcn_mfma_f32_16x16x32_bf16(onesA, pf[qs][1], lacc[qs], 0, 0, 0);
    }
    __builtin_amdgcn_s_setprio(0);

    mw0 = mwn0;
    mw1 = mwn1;
  }

  // epilogue: l lives in row 0 (lanes lq==0, reg 0); broadcast, divide, store
#pragma unroll
  for (int qs = 0; qs < 2; ++qs) {
    float l = __shfl(lacc[qs][0], l15);  // lane l15 holds l for q-col l15
    float inv = 1.f / l;
    float* orow = Op + (size_t)(qbW + qs * 16 + l15) * Dd;
#pragma unroll
    for (int ds = 0; ds < 4; ++ds) {
      f32x4 v = oacc[qs][ds];
      v *= inv;
      *(f32x4*)(orow + ds * 16 + 4 * lq) = v;
    }
  }
}

// ---------------- fallback (round-1 kernel, proven) ----------------
template<bool USEBITS>
__launch_bounds__(256, 2)
__global__ void attn_fwd(const float* __restrict__ Q, const float* __restrict__ K,
                         const float* __restrict__ V, const int* __restrict__ mask,
                         const unsigned long long* __restrict__ mbits,
                         float* __restrict__ Out) {
  __shared__ short Ks[64 * 64];
  __shared__ short Vs[64 * 64];

  const int tid = threadIdx.x;
  const int lane = tid & 63;
  const int w = tid >> 6;
  const int l15 = lane & 15;
  const int lq = lane >> 4;

  const int bid = blockIdx.x;
  const int h = bid & 15;
  const int qt = (bid >> 4) & 7;
  const int b = bid >> 7;

  const int bh = b * Hh + h;
  const float* Qp = Q + (size_t)bh * Ss * Dd;
  const float* Kp = K + (size_t)bh * Ss * Dd;
  const float* Vp = V + (size_t)bh * Ss * Dd;
  float* Op = Out + (size_t)bh * Ss * Dd;

  const int qbW = qt * 256 + w * 64;

  s16x8 qf[4][2];
#pragma unroll
  for (int qs = 0; qs < 4; ++qs) {
    const float* qrow = Qp + (size_t)(qbW + qs * 16 + l15) * Dd;
#pragma unroll
    for (int dh = 0; dh < 2; ++dh) {
      s16x8 f;
#pragma unroll
      for (int g = 0; g < 4; ++g) {
        f32x2 v = *(const f32x2*)(qrow + 16 * g + 4 * lq + 2 * dh);
        f[g] = f2bf(v[0]);
        f[g + 4] = f2bf(v[1]);
      }
      qf[qs][dh] = f;
    }
  }

  f32x4 oacc[4][4];
  float mrun[4], lrun[4];
#pragma unroll
  for (int qs = 0; qs < 4; ++qs) {
    mrun[qs] = -1e30f;
    lrun[qs] = 0.f;
#pragma unroll
    for (int ds = 0; ds < 4; ++ds) oacc[qs][ds] = f32x4{0.f, 0.f, 0.f, 0.f};
  }

  for (int kv0 = 0; kv0 < Ss; kv0 += 64) {
    __syncthreads();
#pragma unroll
    for (int p = 0; p < 4; ++p) {
      int f = tid + p * 256;
      int kv = f >> 4;
      int c = f & 15;
      const float* krow = Kp + (size_t)(kv0 + kv) * Dd;
      s16x4 sv;
      sv[0] = f2bf(krow[c]);
      sv[1] = f2bf(krow[c + 16]);
      sv[2] = f2bf(krow[c + 32]);
      sv[3] = f2bf(krow[c + 48]);
      *(s16x4*)(Ks + kv * 64 + ((4 * c) ^ ((kv & 7) << 3))) = sv;
    }
#pragma unroll
    for (int p = 0; p < 4; ++p) {
      int f = tid + p * 256;
      int kv = f >> 4;
      int c = f & 15;
      f32x4 v = *(const f32x4*)(Vp + (size_t)(kv0 + kv) * Dd + 4 * c);
      int pv = (kv & 15) * 4 + (kv >> 4);
#pragma unroll
      for (int i = 0; i < 4; ++i) {
        int d = 4 * c + i;
        Vs[d * 64 + (pv ^ ((d & 7) << 3))] = f2bf(v[i]);
      }
    }
    __syncthreads();

    s16x8 kf[4][2];
#pragma unroll
    for (int sub = 0; sub < 4; ++sub) {
      int row = sub * 16 + l15;
      const short* base = Ks + row * 64;
      int sw = (row & 7) << 3;
      kf[sub][0] = *(const s16x8*)(base + ((16 * lq + 0) ^ sw));
      kf[sub][1] = *(const s16x8*)(base + ((16 * lq + 8) ^ sw));
    }
    s16x8 vf[4][2];
#pragma unroll
    for (int ds = 0; ds < 4; ++ds) {
      int row = ds * 16 + l15;
      const short* base = Vs + row * 64;
      int sw = (row & 7) << 3;
      vf[ds][0] = *(const s16x8*)(base + ((16 * lq + 0) ^ sw));
      vf[ds][1] = *(const s16x8*)(base + ((16 * lq + 8) ^ sw));
    }

    const int kvw = kv0 >> 6;
#pragma unroll
    for (int qs = 0; qs < 4; ++qs) {
      f32x4 sc[4];
#pragma unroll
      for (int sub = 0; sub < 4; ++sub) {
        f32x4 a = f32x4{0.f, 0.f, 0.f, 0.f};
        a = __builtin_amdgcn_mfma_f32_16x16x32_bf16(kf[sub][0], qf[qs][0], a, 0, 0, 0);
        a = __builtin_amdgcn_mfma_f32_16x16x32_bf16(kf[sub][1], qf[qs][1], a, 0, 0, 0);
        sc[sub] = a;
      }

      const int q = qbW + qs * 16 + l15;
      unsigned long long mw = 0;
      if constexpr (USEBITS) mw = mbits[(size_t)(b * Ss + q) * 32 + kvw];

      float tm = -3e38f;
#pragma unroll
      for (int sub = 0; sub < 4; ++sub) {
        f32x4 s = sc[sub];
        if constexpr (USEBITS) {
          unsigned nib = (unsigned)((mw >> (16 * sub + 4 * lq)) & 0xFULL);
#pragma unroll
          for (int r = 0; r < 4; ++r) {
            float sv = s[r] * SCALE;
            sv = ((nib >> r) & 1u) ? sv : -1e9f;
            s[r] = sv;
            tm = fmaxf(tm, sv);
          }
        } else {
          const int* mrow = mask + ((size_t)b * Ss + q) * Ss + kv0 + 16 * sub + 4 * lq;
          int4 mi = *(const int4*)mrow;
          int mv[4] = {mi.x, mi.y, mi.z, mi.w};
#pragma unroll
          for (int r = 0; r < 4; ++r) {
            float sv = s[r] * SCALE;
            sv = mv[r] ? sv : -1e9f;
            s[r] = sv;
            tm = fmaxf(tm, sv);
          }
        }
        sc[sub] = s;
      }
      tm = fmaxf(tm, __shfl_xor(tm, 16));
      tm = fmaxf(tm, __shfl_xor(tm, 32));
      float mnew = fmaxf(mrun[qs], tm);
      float corr = __expf(mrun[qs] - mnew);
      mrun[qs] = mnew;

      float ps = 0.f;
#pragma unroll
      for (int sub = 0; sub < 4; ++sub) {
        f32x4 s = sc[sub];
#pragma unroll
        for (int r = 0; r < 4; ++r) {
          float p = __expf(s[r] - mnew);
          s[r] = p;
          ps += p;
        }
        sc[sub] = s;
      }
      ps += __shfl_xor(ps, 16);
      ps += __shfl_xor(ps, 32);
      lrun[qs] = lrun[qs] * corr + ps;
#pragma unroll
      for (int ds = 0; ds < 4; ++ds) oacc[qs][ds] *= corr;

      s16x8 pf[2];
#pragma unroll
      for (int kvh = 0; kvh < 2; ++kvh) {
        s16x8 f;
#pragma unroll
        for (int j = 0; j < 8; ++j) f[j] = f2bf(sc[j & 3][2 * kvh + (j >> 2)]);
        pf[kvh] = f;
      }
#pragma unroll
      for (int ds = 0; ds < 4; ++ds) {
        f32x4 a = oacc[qs][ds];
        a = __builtin_amdgcn_mfma_f32_16x16x32_bf16(vf[ds][0], pf[0], a, 0, 0, 0);
        a = __builtin_amdgcn_mfma_f32_16x16x32_bf16(vf[ds][1], pf[1], a, 0, 0, 0);
        oacc[qs][ds] = a;
      }
    }
  }

#pragma unroll
  for (int qs = 0; qs < 4; ++qs) {
    float inv = 1.f / lrun[qs];
    float* orow = Op + (size_t)(qbW + qs * 16 + l15) * Dd;
#pragma unroll
    for (int ds = 0; ds < 4; ++ds) {
      f32x4 v = oacc[qs][ds];
      v *= inv;
      *(f32x4*)(orow + ds * 16 + 4 * lq) = v;
    }
  }
}

extern "C" void kernel_launch(void* const* d_in, const int* in_sizes, int n_in,
                              void* d_out, int out_size, void* d_ws, size_t ws_size,
                              hipStream_t stream) {
  const float* Q = (const float*)d_in[0];
  const float* K = (const float*)d_in[1];
  const float* V = (const float*)d_in[2];
  const int* mask = (const int*)d_in[5];
  float* out = (float*)d_out;

  const int nmask = Bb * Ss * Ss;
  const size_t bitsB = (size_t)(nmask / 64) * 8;          // 2 MiB
  const size_t imgB = (size_t)Bb * Hh * 32 * 4096 * 2;    // 16 MiB each
  const size_t need = bitsB + 2 * imgB;                   // 34 MiB

  if (d_ws && ws_size >= need) {
    unsigned long long* bits = (unsigned long long*)d_ws;
    short* Kimg = (short*)((char*)d_ws + bitsB);
    short* Vimg = (short*)((char*)d_ws + bitsB + imgB);
    mask_to_bits<<<2048, 256, 0, stream>>>(mask, bits, nmask);
    kvconv<<<Bb * Hh * 32 * 2, 256, 0, stream>>>(K, V, Kimg, Vimg);
    attn2<<<Bb * Hh * (Ss / 128), 256, 0, stream>>>(Q, bits, Kimg, Vimg, out);
  } else if (d_ws && ws_size >= bitsB) {
    unsigned long long* bits = (unsigned long long*)d_ws;
    mask_to_bits<<<2048, 256, 0, stream>>>(mask, bits, nmask);
    attn_fwd<true><<<Bb * Hh * (Ss / 256), 256, 0, stream>>>(Q, K, V, mask, bits, out);
  } else {
    attn_fwd<false><<<Bb * Hh * (Ss / 256), 256, 0, stream>>>(Q, K, V, mask, nullptr, out);
  }
}